// Round 2
// baseline (6405.387 us; speedup 1.0000x reference)
//
#include <hip/hip_runtime.h>
#include <hip/hip_bf16.h>
#include <math.h>

// B=8, H=64, W=64, C=512 -> rows M = 32768; T=77, HH=8, DH=64, TOP_M=3
#define MROWS 32768
#define CDIM  512
#define TTOK  77
#define BTOK  616
#define NTOK  16777216

__device__ __forceinline__ float ldin(const void* p, size_t i, int isf32) {
  return isf32 ? ((const float*)p)[i]
               : __bfloat162float(((const __hip_bfloat16*)p)[i]);
}

__device__ __forceinline__ float wave_sum(float v) {
#pragma unroll
  for (int off = 32; off > 0; off >>= 1) v += __shfl_xor(v, off, 64);
  return v;
}
__device__ __forceinline__ float wave_max(float v) {
#pragma unroll
  for (int off = 32; off > 0; off >>= 1) v = fmaxf(v, __shfl_xor(v, off, 64));
  return v;
}
__device__ __forceinline__ float block_sum256(float v) {
  __shared__ float red[4];
  int lane = threadIdx.x & 63, wid = threadIdx.x >> 6;
  float s = wave_sum(v);
  if (lane == 0) red[wid] = s;
  __syncthreads();
  s = red[0] + red[1] + red[2] + red[3];
  __syncthreads();
  return s;
}

// dtype detect: fp32 data -> low 16 bits of each u32 are mantissa garbage
// (~76% insane bf16 exponents); bf16 data -> every half sane. Deterministic.
__global__ __launch_bounds__(256) void detect_kernel(const unsigned int* __restrict__ t,
                                                     int* __restrict__ flag) {
  int insane = 0;
  for (int i = threadIdx.x; i < 4096; i += 256) {
    unsigned int lo = t[i] & 0xFFFFu;
    int e = (int)((lo >> 7) & 0xFFu);
    int sane = (lo == 0u) || (e >= 87 && e <= 147);
    insane += 1 - sane;
  }
  float tot = block_sum256((float)insane);
  if (threadIdx.x == 0) flag[0] = (tot > 1024.0f) ? 1 : 0;  // 1 => fp32 inputs
}

__global__ void cvtp_kernel(const void* __restrict__ in, float* __restrict__ out, int n,
                            const int* __restrict__ flag) {
  int i = blockIdx.x * blockDim.x + threadIdx.x;
  if (i < n) out[i] = ldin(in, i, *flag);
}

__global__ __launch_bounds__(256) void pad_kernel(const float* __restrict__ tf,
                                                  float* __restrict__ pad) {
  int row = blockIdx.x;
  size_t base = (size_t)row * CDIM;
  int tid = threadIdx.x;
  float s = fabsf(tf[base + tid]) + fabsf(tf[base + 256 + tid]);
  float tot = block_sum256(s);
  if (tid == 0) pad[row] = (tot <= 1e-6f) ? 1.0f : 0.0f;
}

template <bool RAW>
__global__ __launch_bounds__(256) void ln_kernel(const void* __restrict__ in,
                                                 const float* __restrict__ w,
                                                 const float* __restrict__ b,
                                                 float* __restrict__ out,
                                                 const int* __restrict__ flag) {
  int row = blockIdx.x;
  size_t base = (size_t)row * CDIM;
  int tid = threadIdx.x;
  float v0, v1;
  if (RAW) {
    int f = *flag;
    v0 = ldin(in, base + tid, f);
    v1 = ldin(in, base + 256 + tid, f);
  } else {
    const float* fin = (const float*)in;
    v0 = fin[base + tid];
    v1 = fin[base + 256 + tid];
  }
  float tot = block_sum256(v0 + v1);
  float mu = tot * (1.0f / 512.0f);
  float d0 = v0 - mu, d1 = v1 - mu;
  float sqs = block_sum256(d0 * d0 + d1 * d1);
  float rs = rsqrtf(sqs * (1.0f / 512.0f) + 1e-5f);
  out[base + tid]       = d0 * rs * w[tid]       + b[tid];
  out[base + 256 + tid] = d1 * rs * w[256 + tid] + b[256 + tid];
}

__global__ __launch_bounds__(256) void rownorm_kernel(float* __restrict__ x) {
  int row = blockIdx.x;
  size_t base = (size_t)row * CDIM;
  int tid = threadIdx.x;
  float v0 = x[base + tid], v1 = x[base + 256 + tid];
  float sq = block_sum256(v0 * v0 + v1 * v1);
  float inv = 1.0f / fmaxf(sqrtf(sq), 1e-6f);
  x[base + tid] = v0 * inv;
  x[base + 256 + tid] = v1 * inv;
}

__global__ __launch_bounds__(256) void gate_kernel(const float* __restrict__ x,
                                                   const float* __restrict__ Wg,
                                                   const float* __restrict__ bg,
                                                   const float* __restrict__ confh,
                                                   const float* __restrict__ alpha_p,
                                                   float* __restrict__ g) {
  int lane = threadIdx.x & 63, wid = threadIdx.x >> 6;
  int row = blockIdx.x * 4 + wid;
  size_t base = (size_t)row * CDIM;
  float acc = 0.0f;
#pragma unroll
  for (int j = 0; j < 8; ++j) acc += x[base + j * 64 + lane] * Wg[j * 64 + lane];
  acc = wave_sum(acc);
  float cs = (lane < 8) ? confh[(size_t)lane * MROWS + row] : 0.0f;
  cs = wave_sum(cs);
  if (lane == 0) {
    float gate = 1.0f / (1.0f + expf(-(acc + bg[0])));
    float byp = (cs * 0.125f >= 0.35f) ? 1.0f : 0.0f;
    g[row] = alpha_p[0] * gate * byp;
  }
}

__global__ void combine_kernel(const float* __restrict__ x, const float* __restrict__ proj,
                               const float* __restrict__ g, float* __restrict__ y) {
  size_t i = (size_t)blockIdx.x * blockDim.x + threadIdx.x;
  int row = (int)(i >> 9);
  y[i] = x[i] + g[row] * proj[i];
}

__global__ __launch_bounds__(256) void attn_kernel(const float* __restrict__ qn,
                                                   const float* __restrict__ kn,
                                                   const float* __restrict__ vf,
                                                   const float* __restrict__ pad,
                                                   const float* __restrict__ ls_p,
                                                   float* __restrict__ aligned,
                                                   float* __restrict__ confh) {
  __shared__ float kt[TTOK * 65];
  __shared__ float vt[TTOK * 65];
  int tid = threadIdx.x;
  int lane = tid & 63, wid = tid >> 6;
  int blk = blockIdx.x;
  int nchunk = blk & 127;
  int bh = blk >> 7;
  int h = bh & 7, b = bh >> 3;

  for (int idx = tid; idx < TTOK * 64; idx += 256) {
    int t = idx >> 6, d = idx & 63;
    size_t src = ((size_t)(b * TTOK + t)) * CDIM + h * 64 + d;
    kt[t * 65 + d] = kn[src];
    vt[t * 65 + d] = vf[src];
  }
  __syncthreads();

  float ls = fminf(fmaxf(ls_p[0], -2.0f), 2.0f);
  float scale = expf(ls) * 0.125f;
  const float NEGINF = -__builtin_inff();
  float pv0 = pad[b * TTOK + lane];
  int t1ok = (lane + 64 < TTOK);
  float pv1 = t1ok ? pad[b * TTOK + lane + 64] : 1.0f;
  int t1 = t1ok ? lane + 64 : 0;

  for (int i = 0; i < 8; ++i) {
    int n = nchunk * 32 + wid * 8 + i;
    size_t qbase = ((size_t)(b * 4096 + n)) * CDIM + h * 64;
    float qv = qn[qbase + lane];
    float s0 = 0.0f, s1 = 0.0f;
#pragma unroll 8
    for (int d = 0; d < 64; ++d) {
      float qd = __shfl(qv, d, 64);
      s0 += qd * kt[lane * 65 + d];
      s1 += qd * kt[t1 * 65 + d];
    }
    float v0 = (pv0 > 0.0f) ? NEGINF : s0 * scale;
    float v1 = (!t1ok || pv1 > 0.0f) ? NEGINF : s1 * scale;

    float m1 = wave_max(fmaxf(v0, v1));
    float a0 = 0.0f, a1 = 0.0f, conf_h = 0.0f;
    unsigned long long km0 = 0ull, km1 = 0ull;
    if (m1 != NEGINF) {
      int c1 = __popcll(__ballot(v0 >= m1)) + __popcll(__ballot(v1 >= m1));
      float thr;
      if (c1 >= 3) thr = m1;
      else {
        float m2 = wave_max(fmaxf(v0 < m1 ? v0 : NEGINF, v1 < m1 ? v1 : NEGINF));
        int c2 = __popcll(__ballot(v0 >= m2)) + __popcll(__ballot(v1 >= m2));
        if (c2 >= 3) thr = m2;
        else thr = wave_max(fmaxf(v0 < m2 ? v0 : NEGINF, v1 < m2 ? v1 : NEGINF));
      }
      float p0 = (v0 >= thr) ? expf(v0 - m1) : 0.0f;
      float p1 = (v1 >= thr) ? expf(v1 - m1) : 0.0f;
      float sum = wave_sum(p0 + p1);
      a0 = p0 / sum; a1 = p1 / sum;
      float sum2 = wave_sum(a0 + a1);
      float rden = 1.0f / fmaxf(sum2, 1e-6f);
      a0 *= rden; a1 *= rden;
      km0 = __ballot(a0 > 0.0f);
      km1 = __ballot(a1 > 0.0f);
      int cnt = __popcll(km0) + __popcll(km1);
      float maxp = wave_max(fmaxf(a0, a1));
      float es = wave_sum((a0 > 0.0f ? -a0 * logf(a0) : 0.0f) +
                          (a1 > 0.0f ? -a1 * logf(a1) : 0.0f));
      es += (float)(TTOK - cnt) * 1.8420680743952367e-7f;
      float teff = fmaxf((float)cnt, 2.0f);
      float ent = fmaxf(es / logf(teff), 0.0f);
      conf_h = fminf(fmaxf(maxp * (1.0f - ent), 0.0f), 1.0f);
    }
    if (lane == 0) confh[(size_t)h * MROWS + b * 4096 + n] = conf_h;

    float acc = 0.0f;
    unsigned long long m = km0;
    while (m) {
      int t = __builtin_ctzll(m);
      acc += __shfl(a0, t, 64) * vt[t * 65 + lane];
      m &= m - 1;
    }
    m = km1;
    while (m) {
      int t = __builtin_ctzll(m);
      acc += __shfl(a1, t, 64) * vt[(t + 64) * 65 + lane];
      m &= m - 1;
    }
    aligned[qbase + lane] = acc;
  }
}

// SGEMM: C = A(f32,MxK) @ B(f32,KxN) + bias; act 1 = exact GELU; optional resid.
// Cfinal: writes to d_out at element offset ooff, fp32 if *flag else bf16.
#define BM 128
#define BN 128
#define BK 16
__global__ __launch_bounds__(256) void sgemm_kernel(const float* __restrict__ A,
                                                    const float* __restrict__ B,
                                                    const float* __restrict__ bias,
                                                    float* __restrict__ Cf,
                                                    void* __restrict__ Cfinal,
                                                    size_t ooff,
                                                    const int* __restrict__ flag,
                                                    const float* __restrict__ resid,
                                                    int M, int N, int K, int act) {
  __shared__ float As[BK][BM];
  __shared__ float Bs[BK][BN];
  int tid = threadIdx.x;
  int bm = blockIdx.y * BM;
  int bn = blockIdx.x * BN;
  int tx = tid & 15, ty = tid >> 4;
  int outf32 = Cfinal ? *flag : 0;
  float acc[8][8] = {};
  for (int k0 = 0; k0 < K; k0 += BK) {
#pragma unroll
    for (int r = 0; r < 8; ++r) {
      int idx = tid + r * 256;
      int row = idx >> 4, kk = idx & 15;
      int gr = bm + row;
      As[kk][row] = (gr < M) ? A[(size_t)gr * K + k0 + kk] : 0.0f;
    }
#pragma unroll
    for (int r = 0; r < 8; ++r) {
      int idx = tid + r * 256;
      int kk = idx >> 7, col = idx & 127;
      Bs[kk][col] = B[(size_t)(k0 + kk) * N + bn + col];
    }
    __syncthreads();
#pragma unroll
    for (int kk = 0; kk < BK; ++kk) {
      float ra[8], rb[8];
#pragma unroll
      for (int i = 0; i < 8; ++i) ra[i] = As[kk][ty * 8 + i];
#pragma unroll
      for (int j = 0; j < 8; ++j) rb[j] = Bs[kk][tx * 8 + j];
#pragma unroll
      for (int i = 0; i < 8; ++i)
#pragma unroll
        for (int j = 0; j < 8; ++j) acc[i][j] += ra[i] * rb[j];
    }
    __syncthreads();
  }
#pragma unroll
  for (int i = 0; i < 8; ++i) {
    int gr = bm + ty * 8 + i;
    if (gr >= M) continue;
#pragma unroll
    for (int j = 0; j < 8; ++j) {
      int gc = bn + tx * 8 + j;
      float v = acc[i][j] + bias[gc];
      if (act == 1) v = 0.5f * v * (1.0f + erff(v * 0.70710678118654752f));
      if (resid) v += resid[(size_t)gr * N + gc];
      size_t oi = (size_t)gr * N + gc;
      if (Cfinal) {
        if (outf32) ((float*)Cfinal)[ooff + oi] = v;
        else        ((__hip_bfloat16*)Cfinal)[ooff + oi] = __float2bfloat16(v);
      } else {
        Cf[oi] = v;
      }
    }
  }
}

extern "C" void kernel_launch(void* const* d_in, const int* in_sizes, int n_in,
                              void* d_out, int out_size, void* d_ws, size_t ws_size,
                              hipStream_t stream) {
  const void* visual = d_in[0];
  const void* text   = d_in[1];

  float* ws   = (float*)d_ws;
  float* xb   = ws;                     // x -> later y2
  float* qb   = ws + (size_t)NTOK;      // q -> proj -> h1 chunks
  float* ab   = ws + (size_t)2 * NTOK;  // aligned -> y
  float* kfb  = ws + (size_t)3 * NTOK;
  float* vfb  = kfb + (size_t)BTOK * CDIM;
  float* tfb  = vfb + (size_t)BTOK * CDIM;
  float* padb = tfb + (size_t)BTOK * CDIM;
  float* confh = padb + BTOK;
  float* gbuf  = confh + (size_t)8 * MROWS;
  float* wp    = gbuf + MROWS;
  float* n1w = wp;            float* n1b = n1w + 512;
  float* n2w = n1b + 512;     float* n2b = n2w + 512;
  float* Wq  = n2b + 512;     float* bq  = Wq + 262144;
  float* Wk  = bq + 512;      float* bk  = Wk + 262144;
  float* Wv  = bk + 512;      float* bv  = Wv + 262144;
  float* Wo  = bv + 512;      float* bo  = Wo + 262144;
  float* Wg  = bo + 512;      float* bg  = Wg + 512;
  float* lsb = bg + 1;
  float* W1  = lsb + 1;       float* b1  = W1 + 1048576;
  float* W2  = b1 + 2048;     float* b2  = W2 + 1048576;
  float* alp = b2 + 512;
  int*   flag = (int*)(alp + 1);

  detect_kernel<<<1, 256, 0, stream>>>((const unsigned int*)text, flag);

  struct CV { const void* src; float* dst; int n; };
  const CV cvs[] = {
    {d_in[2], n1w, 512}, {d_in[3], n1b, 512}, {d_in[4], n2w, 512}, {d_in[5], n2b, 512},
    {d_in[6], Wq, 262144}, {d_in[7], bq, 512}, {d_in[8], Wk, 262144}, {d_in[9], bk, 512},
    {d_in[10], Wv, 262144}, {d_in[11], bv, 512}, {d_in[12], Wo, 262144}, {d_in[13], bo, 512},
    {d_in[14], Wg, 512}, {d_in[15], bg, 1}, {d_in[16], lsb, 1},
    {d_in[17], W1, 1048576}, {d_in[18], b1, 2048}, {d_in[19], W2, 1048576}, {d_in[20], b2, 512},
    {d_in[21], alp, 1},
  };
  for (int i = 0; i < (int)(sizeof(cvs) / sizeof(cvs[0])); ++i)
    cvtp_kernel<<<(cvs[i].n + 255) / 256, 256, 0, stream>>>(cvs[i].src, cvs[i].dst, cvs[i].n, flag);

  cvtp_kernel<<<(BTOK * CDIM + 255) / 256, 256, 0, stream>>>(text, tfb, BTOK * CDIM, flag);
  pad_kernel<<<BTOK, 256, 0, stream>>>(tfb, padb);
  ln_kernel<true><<<MROWS, 256, 0, stream>>>(visual, n1w, n1b, xb, flag);

  sgemm_kernel<<<dim3(4, 256), 256, 0, stream>>>(xb, Wq, bq, qb, nullptr, 0, flag, nullptr, MROWS, 512, 512, 0);
  sgemm_kernel<<<dim3(4, 5), 256, 0, stream>>>(tfb, Wk, bk, kfb, nullptr, 0, flag, nullptr, BTOK, 512, 512, 0);
  sgemm_kernel<<<dim3(4, 5), 256, 0, stream>>>(tfb, Wv, bv, vfb, nullptr, 0, flag, nullptr, BTOK, 512, 512, 0);
  rownorm_kernel<<<MROWS, 256, 0, stream>>>(qb);
  rownorm_kernel<<<BTOK, 256, 0, stream>>>(kfb);

  attn_kernel<<<8 * 8 * 128, 256, 0, stream>>>(qb, kfb, vfb, padb, lsb, ab, confh);

  sgemm_kernel<<<dim3(4, 256), 256, 0, stream>>>(ab, Wo, bo, qb, nullptr, 0, flag, nullptr, MROWS, 512, 512, 0);
  gate_kernel<<<MROWS / 4, 256, 0, stream>>>(xb, Wg, bg, confh, alp, gbuf);
  combine_kernel<<<NTOK / 256, 256, 0, stream>>>(xb, qb, gbuf, ab);
  ln_kernel<false><<<MROWS, 256, 0, stream>>>(ab, n2w, n2b, xb, flag);

  float* h1b = qb;  // qb dead after combine
  for (int c = 0; c < 8; ++c) {
    const float* ychunk = xb + (size_t)c * 4096 * CDIM;
    sgemm_kernel<<<dim3(16, 32), 256, 0, stream>>>(ychunk, W1, b1, h1b, nullptr, 0, flag, nullptr,
                                                   4096, 2048, 512, 1);
    sgemm_kernel<<<dim3(4, 32), 256, 0, stream>>>(h1b, W2, b2, nullptr, d_out,
                                                  (size_t)c * 4096 * CDIM, flag, ychunk,
                                                  4096, 512, 2048, 0);
  }
}

// Round 3
// 1367.142 us; speedup vs baseline: 4.6852x; 4.6852x over previous
//
#include <hip/hip_runtime.h>
#include <hip/hip_bf16.h>
#include <math.h>

// B=8, H=64, W=64, C=512 -> rows M = 32768; T=77, HH=8, DH=64, TOP_M=3
#define MROWS 32768
#define CDIM  512
#define TTOK  77
#define BTOK  616
#define NTOK  16777216

typedef __attribute__((ext_vector_type(8))) short short8;
typedef __attribute__((ext_vector_type(4))) float float4v;

__device__ __forceinline__ float ldin(const void* p, size_t i, int isf32) {
  return isf32 ? ((const float*)p)[i]
               : __bfloat162float(((const __hip_bfloat16*)p)[i]);
}

__device__ __forceinline__ float wave_sum(float v) {
#pragma unroll
  for (int off = 32; off > 0; off >>= 1) v += __shfl_xor(v, off, 64);
  return v;
}
__device__ __forceinline__ float wave_max(float v) {
#pragma unroll
  for (int off = 32; off > 0; off >>= 1) v = fmaxf(v, __shfl_xor(v, off, 64));
  return v;
}
__device__ __forceinline__ float block_sum256(float v) {
  __shared__ float red[4];
  int lane = threadIdx.x & 63, wid = threadIdx.x >> 6;
  float s = wave_sum(v);
  if (lane == 0) red[wid] = s;
  __syncthreads();
  s = red[0] + red[1] + red[2] + red[3];
  __syncthreads();
  return s;
}

// dtype detect (unchanged, proven): 1 => fp32 inputs, 0 => bf16 inputs
__global__ __launch_bounds__(256) void detect_kernel(const unsigned int* __restrict__ t,
                                                     int* __restrict__ flag) {
  int insane = 0;
  for (int i = threadIdx.x; i < 4096; i += 256) {
    unsigned int lo = t[i] & 0xFFFFu;
    int e = (int)((lo >> 7) & 0xFFu);
    int sane = (lo == 0u) || (e >= 87 && e <= 147);
    insane += 1 - sane;
  }
  float tot = block_sum256((float)insane);
  if (threadIdx.x == 0) flag[0] = (tot > 1024.0f) ? 1 : 0;
}

__global__ void cvtp_kernel(const void* __restrict__ in, float* __restrict__ out, int n,
                            const int* __restrict__ flag) {
  int i = blockIdx.x * blockDim.x + threadIdx.x;
  if (i < n) out[i] = ldin(in, i, *flag);
}

// weight transpose+convert: in (KxN, raw dtype) -> out bf16 (NxK)
__global__ __launch_bounds__(256) void tcvt_kernel(const void* __restrict__ in,
                                                   __hip_bfloat16* __restrict__ out,
                                                   int K, int N, const int* __restrict__ flag) {
  __shared__ float tile[32][33];
  int tx = threadIdx.x & 31, ty = threadIdx.x >> 5;   // 32 x 8
  int k0 = blockIdx.y * 32, n0 = blockIdx.x * 32;
  int f = *flag;
#pragma unroll
  for (int r = 0; r < 4; ++r) {
    int k = k0 + ty + r * 8;
    tile[ty + r * 8][tx] = ldin(in, (size_t)k * N + n0 + tx, f);
  }
  __syncthreads();
#pragma unroll
  for (int r = 0; r < 4; ++r) {
    int n = n0 + ty + r * 8;
    out[(size_t)n * K + k0 + tx] = __float2bfloat16(tile[tx][ty + r * 8]);
  }
}

__global__ __launch_bounds__(256) void pad_kernel(const float* __restrict__ tf,
                                                  float* __restrict__ pad) {
  int row = blockIdx.x;
  size_t base = (size_t)row * CDIM;
  int tid = threadIdx.x;
  float s = fabsf(tf[base + tid]) + fabsf(tf[base + 256 + tid]);
  float tot = block_sum256(s);
  if (tid == 0) pad[row] = (tot <= 1e-6f) ? 1.0f : 0.0f;
}

// LayerNorm over C=512 -> bf16 out. RAW: flag-dtype input; else fp32 input.
template <bool RAW>
__global__ __launch_bounds__(256) void ln_kernel(const void* __restrict__ in,
                                                 const float* __restrict__ w,
                                                 const float* __restrict__ b,
                                                 __hip_bfloat16* __restrict__ out,
                                                 const int* __restrict__ flag) {
  int row = blockIdx.x;
  size_t base = (size_t)row * CDIM;
  int tid = threadIdx.x;
  float v0, v1;
  if (RAW) {
    int f = *flag;
    v0 = ldin(in, base + tid, f);
    v1 = ldin(in, base + 256 + tid, f);
  } else {
    const float* fin = (const float*)in;
    v0 = fin[base + tid];
    v1 = fin[base + 256 + tid];
  }
  float tot = block_sum256(v0 + v1);
  float mu = tot * (1.0f / 512.0f);
  float d0 = v0 - mu, d1 = v1 - mu;
  float sqs = block_sum256(d0 * d0 + d1 * d1);
  float rs = rsqrtf(sqs * (1.0f / 512.0f) + 1e-5f);
  out[base + tid]       = __float2bfloat16(d0 * rs * w[tid]       + b[tid]);
  out[base + 256 + tid] = __float2bfloat16(d1 * rs * w[256 + tid] + b[256 + tid]);
}

__global__ __launch_bounds__(256) void rownorm_kernel(float* __restrict__ x) {
  int row = blockIdx.x;
  size_t base = (size_t)row * CDIM;
  int tid = threadIdx.x;
  float v0 = x[base + tid], v1 = x[base + 256 + tid];
  float sq = block_sum256(v0 * v0 + v1 * v1);
  float inv = 1.0f / fmaxf(sqrtf(sq), 1e-6f);
  x[base + tid] = v0 * inv;
  x[base + 256 + tid] = v1 * inv;
}

// g = alpha * sigmoid(x.Wg + bg) * (conf>=0.35); x is bf16 now
__global__ __launch_bounds__(256) void gate_kernel(const __hip_bfloat16* __restrict__ x,
                                                   const float* __restrict__ Wg,
                                                   const float* __restrict__ bg,
                                                   const float* __restrict__ confh,
                                                   const float* __restrict__ alpha_p,
                                                   float* __restrict__ g) {
  int lane = threadIdx.x & 63, wid = threadIdx.x >> 6;
  int row = blockIdx.x * 4 + wid;
  size_t base = (size_t)row * CDIM;
  float acc = 0.0f;
#pragma unroll
  for (int j = 0; j < 8; ++j)
    acc += __bfloat162float(x[base + j * 64 + lane]) * Wg[j * 64 + lane];
  acc = wave_sum(acc);
  float cs = (lane < 8) ? confh[(size_t)lane * MROWS + row] : 0.0f;
  cs = wave_sum(cs);
  if (lane == 0) {
    float gate = 1.0f / (1.0f + expf(-(acc + bg[0])));
    float byp = (cs * 0.125f >= 0.35f) ? 1.0f : 0.0f;
    g[row] = alpha_p[0] * gate * byp;
  }
}

// y[i] = x[i] + g[row]*y[i]   (in-place over proj)
__global__ void combine_kernel(const __hip_bfloat16* __restrict__ x,
                               float* __restrict__ y, const float* __restrict__ g) {
  size_t i = (size_t)blockIdx.x * blockDim.x + threadIdx.x;
  int row = (int)(i >> 9);
  y[i] = __bfloat162float(x[i]) + g[row] * y[i];
}

// ---------------- attention ----------------
__global__ __launch_bounds__(256) void attn_kernel(const float* __restrict__ qn,
                                                   const float* __restrict__ kn,
                                                   const float* __restrict__ vf,
                                                   const float* __restrict__ pad,
                                                   const float* __restrict__ ls_p,
                                                   __hip_bfloat16* __restrict__ aligned,
                                                   float* __restrict__ confh) {
  __shared__ float kt[TTOK * 68];
  __shared__ float vt[TTOK * 68];
  __shared__ float qt[32 * 64];
  int tid = threadIdx.x;
  int lane = tid & 63, wid = tid >> 6;
  int blk = blockIdx.x;
  int nchunk = blk & 127;
  int bh = blk >> 7;
  int h = bh & 7, b = bh >> 3;

  for (int idx = tid; idx < TTOK * 64; idx += 256) {
    int t = idx >> 6, d = idx & 63;
    size_t src = ((size_t)(b * TTOK + t)) * CDIM + h * 64 + d;
    kt[t * 68 + d] = kn[src];
    vt[t * 68 + d] = vf[src];
  }
  for (int idx = tid; idx < 32 * 64; idx += 256) {
    int nl = idx >> 6, d = idx & 63;
    qt[idx] = qn[((size_t)(b * 4096 + nchunk * 32 + nl)) * CDIM + h * 64 + d];
  }
  __syncthreads();

  float ls = fminf(fmaxf(ls_p[0], -2.0f), 2.0f);
  float scale = expf(ls) * 0.125f;
  const float NEGINF = -__builtin_inff();
  float pv0 = pad[b * TTOK + lane];
  int t1ok = (lane + 64 < TTOK);
  float pv1 = t1ok ? pad[b * TTOK + lane + 64] : 1.0f;
  int t1 = t1ok ? lane + 64 : 0;

  for (int i = 0; i < 8; ++i) {
    int nl = wid * 8 + i;
    int n = nchunk * 32 + nl;
    size_t qbase = ((size_t)(b * 4096 + n)) * CDIM + h * 64;
    float s0 = 0.0f, s1 = 0.0f;
    const float4* qv4 = (const float4*)&qt[nl * 64];
    const float4* k0p = (const float4*)&kt[lane * 68];
    const float4* k1p = (const float4*)&kt[t1 * 68];
#pragma unroll
    for (int dg = 0; dg < 16; ++dg) {
      float4 qq = qv4[dg];
      float4 ka = k0p[dg];
      float4 kb = k1p[dg];
      s0 += qq.x * ka.x + qq.y * ka.y + qq.z * ka.z + qq.w * ka.w;
      s1 += qq.x * kb.x + qq.y * kb.y + qq.z * kb.z + qq.w * kb.w;
    }
    float v0 = (pv0 > 0.0f) ? NEGINF : s0 * scale;
    float v1 = (!t1ok || pv1 > 0.0f) ? NEGINF : s1 * scale;

    float m1 = wave_max(fmaxf(v0, v1));
    float a0 = 0.0f, a1 = 0.0f, conf_h = 0.0f;
    unsigned long long km0 = 0ull, km1 = 0ull;
    if (m1 != NEGINF) {
      int c1 = __popcll(__ballot(v0 >= m1)) + __popcll(__ballot(v1 >= m1));
      float thr;
      if (c1 >= 3) thr = m1;
      else {
        float m2 = wave_max(fmaxf(v0 < m1 ? v0 : NEGINF, v1 < m1 ? v1 : NEGINF));
        int c2 = __popcll(__ballot(v0 >= m2)) + __popcll(__ballot(v1 >= m2));
        if (c2 >= 3) thr = m2;
        else thr = wave_max(fmaxf(v0 < m2 ? v0 : NEGINF, v1 < m2 ? v1 : NEGINF));
      }
      float p0 = (v0 >= thr) ? expf(v0 - m1) : 0.0f;
      float p1 = (v1 >= thr) ? expf(v1 - m1) : 0.0f;
      float sum = wave_sum(p0 + p1);
      a0 = p0 / sum; a1 = p1 / sum;
      float sum2 = wave_sum(a0 + a1);
      float rden = 1.0f / fmaxf(sum2, 1e-6f);
      a0 *= rden; a1 *= rden;
      km0 = __ballot(a0 > 0.0f);
      km1 = __ballot(a1 > 0.0f);
      int cnt = __popcll(km0) + __popcll(km1);
      float maxp = wave_max(fmaxf(a0, a1));
      float es = wave_sum((a0 > 0.0f ? -a0 * logf(a0) : 0.0f) +
                          (a1 > 0.0f ? -a1 * logf(a1) : 0.0f));
      es += (float)(TTOK - cnt) * 1.8420680743952367e-7f;
      float teff = fmaxf((float)cnt, 2.0f);
      float ent = fmaxf(es / logf(teff), 0.0f);
      conf_h = fminf(fmaxf(maxp * (1.0f - ent), 0.0f), 1.0f);
    }
    if (lane == 0) confh[(size_t)h * MROWS + b * 4096 + n] = conf_h;

    float acc = 0.0f;
    unsigned long long m = km0;
    while (m) {
      int t = __builtin_ctzll(m);
      acc += __shfl(a0, t, 64) * vt[t * 68 + lane];
      m &= m - 1;
    }
    m = km1;
    while (m) {
      int t = __builtin_ctzll(m);
      acc += __shfl(a1, t, 64) * vt[(t + 64) * 68 + lane];
      m &= m - 1;
    }
    aligned[qbase + lane] = __float2bfloat16(acc);
  }
}

// ---------------- bf16 MFMA GEMM: C = A(MxK bf16) @ BT^T + bias ----------------
// BT is N x K bf16 (pre-transposed weights). M%128==0, N%128==0, K%32==0.
// mode 0: out bf16; mode 1: out fp32; mode 2: out d_out (fp32 if *flag else bf16) at ooff.
// act 1 = exact GELU. resid optional fp32.
__global__ __launch_bounds__(256) void mfma_gemm(const short* __restrict__ A,
                                                 const short* __restrict__ BT,
                                                 const float* __restrict__ bias,
                                                 void* __restrict__ outp,
                                                 int mode, size_t ooff,
                                                 const int* __restrict__ flag,
                                                 const float* __restrict__ resid,
                                                 int M, int N, int K, int act) {
  __shared__ short As[128 * 40];
  __shared__ short Bs[128 * 40];
  int tid = threadIdx.x;
  int lane = tid & 63, w = tid >> 6;
  int wr = w >> 1, wc = w & 1;
  int bm = blockIdx.y * 128, bn = blockIdx.x * 128;
  float4v acc[4][4];
#pragma unroll
  for (int i = 0; i < 4; ++i)
#pragma unroll
    for (int j = 0; j < 4; ++j) acc[i][j] = (float4v){0.f, 0.f, 0.f, 0.f};

  int lrow = tid >> 2;            // 0..63
  int lcg  = (tid & 3) * 8;       // 0,8,16,24
  const short* Ag = A + (size_t)bm * K;
  const short* Bg = BT + (size_t)bn * K;
  int m0 = wr * 64 + (lane & 15);
  int n0 = wc * 64 + (lane & 15);
  int kg = (lane >> 4) * 8;

  for (int k0 = 0; k0 < K; k0 += 32) {
    short8 a0 = *(const short8*)(Ag + (size_t)lrow * K + k0 + lcg);
    short8 a1 = *(const short8*)(Ag + (size_t)(lrow + 64) * K + k0 + lcg);
    short8 b0 = *(const short8*)(Bg + (size_t)lrow * K + k0 + lcg);
    short8 b1 = *(const short8*)(Bg + (size_t)(lrow + 64) * K + k0 + lcg);
    __syncthreads();
    *(short8*)&As[lrow * 40 + lcg] = a0;
    *(short8*)&As[(lrow + 64) * 40 + lcg] = a1;
    *(short8*)&Bs[lrow * 40 + lcg] = b0;
    *(short8*)&Bs[(lrow + 64) * 40 + lcg] = b1;
    __syncthreads();
    short8 af[4], bf[4];
#pragma unroll
    for (int mi = 0; mi < 4; ++mi) af[mi] = *(const short8*)&As[(m0 + mi * 16) * 40 + kg];
#pragma unroll
    for (int ni = 0; ni < 4; ++ni) bf[ni] = *(const short8*)&Bs[(n0 + ni * 16) * 40 + kg];
#pragma unroll
    for (int mi = 0; mi < 4; ++mi)
#pragma unroll
      for (int ni = 0; ni < 4; ++ni)
        acc[mi][ni] = __builtin_amdgcn_mfma_f32_16x16x32_bf16(af[mi], bf[ni], acc[mi][ni], 0, 0, 0);
  }

  int outf32 = (mode == 2) ? *flag : 0;
#pragma unroll
  for (int mi = 0; mi < 4; ++mi) {
#pragma unroll
    for (int ni = 0; ni < 4; ++ni) {
#pragma unroll
      for (int r = 0; r < 4; ++r) {
        int gr = bm + wr * 64 + mi * 16 + (lane >> 4) * 4 + r;
        int gc = bn + wc * 64 + ni * 16 + (lane & 15);
        float v = acc[mi][ni][r] + bias[gc];
        if (act == 1) v = 0.5f * v * (1.0f + erff(v * 0.70710678118654752f));
        if (resid) v += resid[(size_t)gr * N + gc];
        size_t oi = (size_t)gr * N + gc;
        if (mode == 0)      ((__hip_bfloat16*)outp)[oi] = __float2bfloat16(v);
        else if (mode == 1) ((float*)outp)[oi] = v;
        else {
          if (outf32) ((float*)outp)[ooff + oi] = v;
          else        ((__hip_bfloat16*)outp)[ooff + oi] = __float2bfloat16(v);
        }
      }
    }
  }
}

// ---------------- small fp32 SGEMM (k/v only: M=616) ----------------
#define BM 128
#define BN 128
#define BK 16
__global__ __launch_bounds__(256) void sgemm_kernel(const float* __restrict__ A,
                                                    const float* __restrict__ B,
                                                    const float* __restrict__ bias,
                                                    float* __restrict__ Cf,
                                                    int M, int N, int K) {
  __shared__ float As[BK][BM];
  __shared__ float Bs[BK][BN];
  int tid = threadIdx.x;
  int bm = blockIdx.y * BM;
  int bn = blockIdx.x * BN;
  int tx = tid & 15, ty = tid >> 4;
  float acc[8][8] = {};
  for (int k0 = 0; k0 < K; k0 += BK) {
#pragma unroll
    for (int r = 0; r < 8; ++r) {
      int idx = tid + r * 256;
      int row = idx >> 4, kk = idx & 15;
      int gr = bm + row;
      As[kk][row] = (gr < M) ? A[(size_t)gr * K + k0 + kk] : 0.0f;
    }
#pragma unroll
    for (int r = 0; r < 8; ++r) {
      int idx = tid + r * 256;
      int kk = idx >> 7, col = idx & 127;
      Bs[kk][col] = B[(size_t)(k0 + kk) * N + bn + col];
    }
    __syncthreads();
#pragma unroll
    for (int kk = 0; kk < BK; ++kk) {
      float ra[8], rb[8];
#pragma unroll
      for (int i = 0; i < 8; ++i) ra[i] = As[kk][ty * 8 + i];
#pragma unroll
      for (int j = 0; j < 8; ++j) rb[j] = Bs[kk][tx * 8 + j];
#pragma unroll
      for (int i = 0; i < 8; ++i)
#pragma unroll
        for (int j = 0; j < 8; ++j) acc[i][j] += ra[i] * rb[j];
    }
    __syncthreads();
  }
#pragma unroll
  for (int i = 0; i < 8; ++i) {
    int gr = bm + ty * 8 + i;
    if (gr >= M) continue;
#pragma unroll
    for (int j = 0; j < 8; ++j) {
      int gc = bn + tx * 8 + j;
      Cf[(size_t)gr * N + gc] = acc[i][j] + bias[gc];
    }
  }
}

extern "C" void kernel_launch(void* const* d_in, const int* in_sizes, int n_in,
                              void* d_out, int out_size, void* d_ws, size_t ws_size,
                              hipStream_t stream) {
  const void* visual = d_in[0];
  const void* text   = d_in[1];

  // ---- workspace layout (byte offsets, all 16B aligned) ----
  char* wsb = (char*)d_ws;
  size_t off = 0;
  auto alloc = [&](size_t bytes) { char* p = wsb + off; off += (bytes + 63) & ~63ull; return p; };

  float* qpy  = (float*)alloc((size_t)NTOK * 4);            // q -> proj -> y (fp32)
  __hip_bfloat16* xb2 = (__hip_bfloat16*)alloc((size_t)NTOK * 2);  // x bf16 -> y2 bf16
  __hip_bfloat16* alb = (__hip_bfloat16*)alloc((size_t)NTOK * 2);  // aligned bf16
  __hip_bfloat16* h1b = (__hip_bfloat16*)alloc((size_t)8192 * 2048 * 2); // MLP hidden chunk
  float* kfb  = (float*)alloc((size_t)BTOK * CDIM * 4);
  float* vfb  = (float*)alloc((size_t)BTOK * CDIM * 4);
  float* tfb  = (float*)alloc((size_t)BTOK * CDIM * 4);
  float* padb = (float*)alloc(BTOK * 4);
  float* confh = (float*)alloc((size_t)8 * MROWS * 4);
  float* gbuf  = (float*)alloc(MROWS * 4);
  // fp32 params
  float* n1w = (float*)alloc(512 * 4);  float* n1b = (float*)alloc(512 * 4);
  float* n2w = (float*)alloc(512 * 4);  float* n2b = (float*)alloc(512 * 4);
  float* bq  = (float*)alloc(512 * 4);  float* bk = (float*)alloc(512 * 4);
  float* bv  = (float*)alloc(512 * 4);  float* bo = (float*)alloc(512 * 4);
  float* Wgf = (float*)alloc(512 * 4);  float* bg = (float*)alloc(16);
  float* lsb = (float*)alloc(16);
  float* b1  = (float*)alloc(2048 * 4); float* b2 = (float*)alloc(512 * 4);
  float* alp = (float*)alloc(16);
  float* Wkf = (float*)alloc((size_t)262144 * 4);
  float* Wvf = (float*)alloc((size_t)262144 * 4);
  // bf16 transposed weights (N x K)
  __hip_bfloat16* WqT = (__hip_bfloat16*)alloc((size_t)262144 * 2);
  __hip_bfloat16* WoT = (__hip_bfloat16*)alloc((size_t)262144 * 2);
  __hip_bfloat16* W1T = (__hip_bfloat16*)alloc((size_t)1048576 * 2);
  __hip_bfloat16* W2T = (__hip_bfloat16*)alloc((size_t)1048576 * 2);
  int* flag = (int*)alloc(16);

  detect_kernel<<<1, 256, 0, stream>>>((const unsigned int*)text, flag);

  struct CV { const void* src; float* dst; int n; };
  const CV cvs[] = {
    {d_in[2], n1w, 512}, {d_in[3], n1b, 512}, {d_in[4], n2w, 512}, {d_in[5], n2b, 512},
    {d_in[7], bq, 512}, {d_in[9], bk, 512}, {d_in[11], bv, 512}, {d_in[13], bo, 512},
    {d_in[14], Wgf, 512}, {d_in[15], bg, 1}, {d_in[16], lsb, 1},
    {d_in[18], b1, 2048}, {d_in[20], b2, 512}, {d_in[21], alp, 1},
    {d_in[8], Wkf, 262144}, {d_in[10], Wvf, 262144},
  };
  for (int i = 0; i < (int)(sizeof(cvs) / sizeof(cvs[0])); ++i)
    cvtp_kernel<<<(cvs[i].n + 255) / 256, 256, 0, stream>>>(cvs[i].src, cvs[i].dst, cvs[i].n, flag);

  // transpose-convert MFMA weights to bf16 NxK
  tcvt_kernel<<<dim3(512 / 32, 512 / 32), 256, 0, stream>>>(d_in[6],  WqT, 512, 512, flag);
  tcvt_kernel<<<dim3(512 / 32, 512 / 32), 256, 0, stream>>>(d_in[12], WoT, 512, 512, flag);
  tcvt_kernel<<<dim3(2048 / 32, 512 / 32), 256, 0, stream>>>(d_in[17], W1T, 512, 2048, flag);
  tcvt_kernel<<<dim3(512 / 32, 2048 / 32), 256, 0, stream>>>(d_in[19], W2T, 2048, 512, flag);

  cvtp_kernel<<<(BTOK * CDIM + 255) / 256, 256, 0, stream>>>(text, tfb, BTOK * CDIM, flag);
  pad_kernel<<<BTOK, 256, 0, stream>>>(tfb, padb);
  ln_kernel<true><<<MROWS, 256, 0, stream>>>(visual, n1w, n1b, xb2, flag);

  // q = x @ Wq + bq  (MFMA, fp32 out)
  mfma_gemm<<<dim3(4, 256), 256, 0, stream>>>((const short*)xb2, (const short*)WqT, bq,
                                              qpy, 1, 0, flag, nullptr, MROWS, 512, 512, 0);
  // k,v (fp32 sgemm, small)
  sgemm_kernel<<<dim3(4, 5), 256, 0, stream>>>(tfb, Wkf, bk, kfb, BTOK, 512, 512);
  sgemm_kernel<<<dim3(4, 5), 256, 0, stream>>>(tfb, Wvf, bv, vfb, BTOK, 512, 512);
  rownorm_kernel<<<MROWS, 256, 0, stream>>>(qpy);
  rownorm_kernel<<<BTOK, 256, 0, stream>>>(kfb);

  attn_kernel<<<8 * 8 * 128, 256, 0, stream>>>(qpy, kfb, vfb, padb, lsb, alb, confh);

  // proj = aligned @ Wo + bo  (MFMA, fp32 out into qpy; q dead)
  mfma_gemm<<<dim3(4, 256), 256, 0, stream>>>((const short*)alb, (const short*)WoT, bo,
                                              qpy, 1, 0, flag, nullptr, MROWS, 512, 512, 0);
  gate_kernel<<<MROWS / 4, 256, 0, stream>>>(xb2, Wgf, bg, confh, alp, gbuf);
  combine_kernel<<<NTOK / 256, 256, 0, stream>>>(xb2, qpy, gbuf);       // y in qpy
  ln_kernel<false><<<MROWS, 256, 0, stream>>>(qpy, n2w, n2b, xb2, flag); // y2 bf16 in xb2

  // MLP in 4 chunks of 8192 rows
  for (int c = 0; c < 4; ++c) {
    const short* ychunk = (const short*)(xb2 + (size_t)c * 8192 * CDIM);
    const float* yres   = qpy + (size_t)c * 8192 * CDIM;
    mfma_gemm<<<dim3(16, 64), 256, 0, stream>>>(ychunk, (const short*)W1T, b1,
                                                h1b, 0, 0, flag, nullptr, 8192, 2048, 512, 1);
    mfma_gemm<<<dim3(4, 64), 256, 0, stream>>>((const short*)h1b, (const short*)W2T, b2,
                                               d_out, 2, (size_t)c * 8192 * CDIM, flag, yres,
                                               8192, 512, 2048, 0);
  }
}